// Round 13
// baseline (565.586 us; speedup 1.0000x reference)
//
#include <hip/hip_runtime.h>

constexpr int kC  = 20;              // NUM_CLASSES
constexpr int kP  = 8192;            // NUM_PARCELS
constexpr int kIgnore = 255;         // IGNORE_INDEX
constexpr int kHW = 512 * 512;       // 2^18
constexpr int kM  = 8 * kHW;         // 2097152 pixels

constexpr int NB1 = 256;             // sort chunks
constexpr int CH1 = kM / NB1;        // 8192 pixels per chunk

// ---- workspace layout (bytes) ----
// off(hist in place) | cnt | first | bin | accum | [minb / sortedV alias]
constexpr size_t oOff   = 0;                                   // NB1*kP*4 = 8,388,608
constexpr size_t oCnt   = oOff + (size_t)NB1 * kP * 4;         // 8,388,608
constexpr size_t oFirst = oCnt + (size_t)kP * 4;               // 8,421,376
constexpr size_t oBin   = oFirst + (size_t)kP * 4;             // 8,454,144
constexpr size_t oAcc   = oBin + (size_t)kP * 4;               // 8,486,912
constexpr size_t oSort  = oAcc + 256;                          // 8,487,168 (64B aligned)
constexpr size_t oMinb  = oSort;                               // minb (8MB) dead after kB; sortedV reuses
constexpr size_t kNeed64 = oSort + (size_t)kM * 64;            // 142,704,896
constexpr size_t kNeed40 = oSort + (size_t)kM * 40;            // 92,373,248  (< proven ws >= 93,028,608)

__device__ inline unsigned bf16rne(float x) {
    unsigned u = __float_as_uint(x);
    return (u + 0x7fffu + ((u >> 16) & 1u)) >> 16;   // RNE, no NaN in data
}

// ---- kA: per-chunk histogram + per-chunk min valid pixel index ----
__global__ __launch_bounds__(1024)
void kA_hist(const int* __restrict__ target, const int* __restrict__ parcel,
             int* __restrict__ hist, int* __restrict__ minb) {
    __shared__ int lh[kP];
    __shared__ int lm[kP];
    const int b = blockIdx.x;
    for (int p = threadIdx.x; p < kP; p += 1024) { lh[p] = 0; lm[p] = kM; }
    __syncthreads();
    const int base = b * CH1;
    for (int j = threadIdx.x; j < CH1; j += 1024) {
        const int i = base + j;
        if (target[i] != kIgnore) {
            const int p = parcel[i];
            atomicAdd(&lh[p], 1);
            atomicMin(&lm[p], i);
        }
    }
    __syncthreads();
    int* hb = hist + (size_t)b * kP;
    int* mb = minb + (size_t)b * kP;
    for (int p = threadIdx.x; p < kP; p += 1024) { hb[p] = lh[p]; mb[p] = lm[p]; }
}

// ---- kB: column scan over chunks; hist -> per-chunk offsets in place; cnt/first; zero accum ----
__global__ __launch_bounds__(256)
void kB_colscan(int* __restrict__ histoff, const int* __restrict__ minb,
                int* __restrict__ cnt, int* __restrict__ first, float* __restrict__ accum) {
    const int p = blockIdx.x * 256 + threadIdx.x;   // 32 blocks
    int run = 0, mn = kM;
    for (int b = 0; b < NB1; ++b) {
        const size_t o = (size_t)b * kP + p;
        const int h = histoff[o];
        histoff[o] = run;            // same-thread read-then-write: safe
        run += h;
        mn = min(mn, minb[o]);
    }
    cnt[p] = run;
    first[p] = mn;
    if (p < 2) accum[p] = 0.0f;
}

// ---- k3: exclusive scan of cnt -> binstart ----
__global__ __launch_bounds__(256)
void k3_scan(const int* __restrict__ cnt, int* __restrict__ binstart) {
    __shared__ int part[256];
    const int t = threadIdx.x;
    constexpr int seg = kP / 256;   // 32
    int loc[seg];
    int s = 0;
    const int base = t * seg;
#pragma unroll
    for (int j = 0; j < seg; ++j) { loc[j] = s; s += cnt[base + j]; }
    part[t] = s;
    __syncthreads();
    if (t == 0) {
        int r = 0;
        for (int i = 0; i < 256; ++i) { const int v = part[i]; part[i] = r; r += v; }
    }
    __syncthreads();
    const int pb = part[t];
#pragma unroll
    for (int j = 0; j < seg; ++j) binstart[base + j] = pb + loc[j];
}

// ---- k5v<RD>: counting-sort scatter of bf16 rows (RD dwords row stride) ----
template <int RD>
__global__ __launch_bounds__(1024)
void k5v(const int* __restrict__ target, const int* __restrict__ parcel,
         const float* __restrict__ pred, const int* __restrict__ off,
         const int* __restrict__ binstart, unsigned* __restrict__ sortedV) {
    __shared__ int cur[kP];
    const int b = blockIdx.x;
    const int* ob = off + (size_t)b * kP;
    for (int p = threadIdx.x; p < kP; p += 1024) cur[p] = binstart[p] + ob[p];
    __syncthreads();
    const int base = b * CH1;
    for (int j = threadIdx.x * 2; j < CH1; j += 2048) {   // 4 iters, pixel pairs
        const int i = base + j;                            // even; chunk stays in one image
        const int t0 = target[i], t1 = target[i + 1];
        const int p0 = parcel[i], p1 = parcel[i + 1];
        const int n = i >> 18, hw = i & (kHW - 1);
        const float* pp = pred + ((size_t)(n * kC) << 18) + hw;
        float2 v[kC];
#pragma unroll
        for (int c = 0; c < kC; ++c) v[c] = *reinterpret_cast<const float2*>(pp + ((size_t)c << 18));
        if (t0 != kIgnore) {
            const int pos = atomicAdd(&cur[p0], 1);        // 1 LDS atomic per pixel
            unsigned w[10];
#pragma unroll
            for (int q = 0; q < 10; ++q)
                w[q] = bf16rne(v[2 * q].x) | (bf16rne(v[2 * q + 1].x) << 16);
            unsigned* dst = sortedV + (size_t)pos * RD;
            if constexpr (RD == 16) {                      // full-64B-line writes, no RMW
                *reinterpret_cast<uint4*>(dst)      = make_uint4(w[0], w[1], w[2], w[3]);
                *reinterpret_cast<uint4*>(dst + 4)  = make_uint4(w[4], w[5], w[6], w[7]);
                *reinterpret_cast<uint4*>(dst + 8)  = make_uint4(w[8], w[9], 0u, 0u);
                *reinterpret_cast<uint4*>(dst + 12) = make_uint4(0u, 0u, 0u, 0u);
            } else {
#pragma unroll
                for (int q = 0; q < 5; ++q)
                    reinterpret_cast<uint2*>(dst)[q] = make_uint2(w[2 * q], w[2 * q + 1]);
            }
        }
        if (t1 != kIgnore) {
            const int pos = atomicAdd(&cur[p1], 1);
            unsigned w[10];
#pragma unroll
            for (int q = 0; q < 10; ++q)
                w[q] = bf16rne(v[2 * q].y) | (bf16rne(v[2 * q + 1].y) << 16);
            unsigned* dst = sortedV + (size_t)pos * RD;
            if constexpr (RD == 16) {
                *reinterpret_cast<uint4*>(dst)      = make_uint4(w[0], w[1], w[2], w[3]);
                *reinterpret_cast<uint4*>(dst + 4)  = make_uint4(w[4], w[5], w[6], w[7]);
                *reinterpret_cast<uint4*>(dst + 8)  = make_uint4(w[8], w[9], 0u, 0u);
                *reinterpret_cast<uint4*>(dst + 12) = make_uint4(0u, 0u, 0u, 0u);
            } else {
#pragma unroll
                for (int q = 0; q < 5; ++q)
                    reinterpret_cast<uint2*>(dst)[q] = make_uint2(w[2 * q], w[2 * q + 1]);
            }
        }
    }
}

// ---- k6v<RD>: wave-per-parcel coalesced segment reduce + fused balanced-softmax NLL ----
template <int RD>
__global__ __launch_bounds__(256)
void k6v(const unsigned* __restrict__ sortedV, const int* __restrict__ binstart,
         const int* __restrict__ cnt, const int* __restrict__ first,
         const int* __restrict__ target, const int* __restrict__ cls_num,
         float* __restrict__ accum) {
    const int wid = threadIdx.x >> 6, lane = threadIdx.x & 63;
    const int p = blockIdx.x * 4 + wid;    // 2048 blocks
    const int c0 = binstart[p];
    const int n  = cnt[p];
    float acc[kC];
#pragma unroll
    for (int c = 0; c < kC; ++c) acc[c] = 0.0f;
    for (int r = lane; r < n; r += 64) {
        const unsigned* row = sortedV + (size_t)(c0 + r) * RD;
        unsigned w[10];
        if constexpr (RD == 16) {
            const uint4 a0 = *reinterpret_cast<const uint4*>(row);
            const uint4 a1 = *reinterpret_cast<const uint4*>(row + 4);
            const uint2 a2 = *reinterpret_cast<const uint2*>(row + 8);
            w[0]=a0.x; w[1]=a0.y; w[2]=a0.z; w[3]=a0.w;
            w[4]=a1.x; w[5]=a1.y; w[6]=a1.z; w[7]=a1.w;
            w[8]=a2.x; w[9]=a2.y;
        } else {
#pragma unroll
            for (int q = 0; q < 5; ++q) {
                const uint2 u = reinterpret_cast<const uint2*>(row)[q];
                w[2*q] = u.x; w[2*q+1] = u.y;
            }
        }
#pragma unroll
        for (int q = 0; q < 10; ++q) {
            acc[2*q]   += __uint_as_float(w[q] << 16);
            acc[2*q+1] += __uint_as_float(w[q] & 0xffff0000u);
        }
    }
#pragma unroll
    for (int c = 0; c < kC; ++c) {
        float v = acc[c];
#pragma unroll
        for (int o = 32; o > 0; o >>= 1) v += __shfl_xor(v, o);
        acc[c] = v;
    }
    if (lane == 0 && n > 0) {
        int f = first[p]; if (f > kM - 1) f = kM - 1;
        const int label = target[f];
        const float inv = 1.0f / (float)n;
        float bal[kC]; float m = -3.402823466e38f;
#pragma unroll
        for (int c = 0; c < kC; ++c) {
            bal[c] = acc[c] * inv + logf((float)cls_num[c]);
            m = fmaxf(m, bal[c]);
        }
        float s = 0.0f;
#pragma unroll
        for (int c = 0; c < kC; ++c) s += expf(bal[c] - m);
        const float lse = m + logf(s);
        float nll = 0.0f;
        if (label >= 0 && label < kC) nll = lse - bal[label];
        atomicAdd(&accum[0], nll);
        atomicAdd(&accum[1], 1.0f);
    }
}

__global__ void kE_out(const float* __restrict__ accum, float* __restrict__ out) {
    out[0] = accum[0] / fmaxf(accum[1], 1.0f);
}

// ---- atomic fallback (proven round-2 path; only if ws is tiny — not expected) ----
__global__ __launch_bounds__(256)
void fb_init(float* seg, float* cnt, int* first, float* accum) {
    const int i = blockIdx.x * blockDim.x + threadIdx.x;
    if (i < kP * kC) seg[i] = 0.0f;
    if (i < kP) { cnt[i] = 0.0f; first[i] = kM; }
    if (i < 2) accum[i] = 0.0f;
}
__global__ __launch_bounds__(256)
void fb_scatter(const float* __restrict__ pred, const int* __restrict__ target,
                const int* __restrict__ parcel, float* seg, float* cnt, int* first) {
    const int stride = gridDim.x * blockDim.x;
    for (int idx = blockIdx.x * blockDim.x + threadIdx.x; idx < kM; idx += stride) {
        const int t = target[idx];
        if (t == kIgnore) continue;
        const int p = parcel[idx];
        const int n = idx >> 18, hw = idx & (kHW - 1);
        const float* base = pred + (size_t)n * kC * kHW + hw;
        float* srow = seg + p * kC;
#pragma unroll
        for (int c = 0; c < kC; ++c) atomicAdd(&srow[c], base[(size_t)c * kHW]);
        atomicAdd(&cnt[p], 1.0f);
        atomicMin(&first[p], idx);
    }
}
__global__ __launch_bounds__(256)
void fb_finalize(const float* __restrict__ seg, const float* __restrict__ cnt,
                 const int* __restrict__ first, const int* __restrict__ target,
                 const int* __restrict__ cls_num, float* __restrict__ accum) {
    __shared__ float logcls[kC];
    if (threadIdx.x < kC) logcls[threadIdx.x] = logf((float)cls_num[threadIdx.x]);
    __syncthreads();
    const int p = blockIdx.x * blockDim.x + threadIdx.x;
    float nll = 0.0f, pres = 0.0f;
    if (p < kP) {
        const float c = cnt[p];
        if (c > 0.0f) {
            int f = first[p]; if (f > kM - 1) f = kM - 1;
            const int label = target[f];
            const float inv = 1.0f / c;
            float bal[kC]; float m = -3.402823466e38f;
#pragma unroll
            for (int k = 0; k < kC; ++k) {
                bal[k] = seg[p * kC + k] * inv + logcls[k];
                m = fmaxf(m, bal[k]);
            }
            float s = 0.0f;
#pragma unroll
            for (int k = 0; k < kC; ++k) s += expf(bal[k] - m);
            const float lse = m + logf(s);
            pres = 1.0f;
            if (label >= 0 && label < kC) nll = lse - bal[label];
        }
    }
    float a = nll, b = pres;
#pragma unroll
    for (int o = 32; o > 0; o >>= 1) { a += __shfl_down(a, o); b += __shfl_down(b, o); }
    __shared__ float wsum[4], wcnt[4];
    const int lane = threadIdx.x & 63, wid = threadIdx.x >> 6;
    if (lane == 0) { wsum[wid] = a; wcnt[wid] = b; }
    __syncthreads();
    if (threadIdx.x == 0) {
        float sa = 0.0f, sb = 0.0f;
        for (int w = 0; w < 4; ++w) { sa += wsum[w]; sb += wcnt[w]; }
        atomicAdd(&accum[0], sa);
        atomicAdd(&accum[1], sb);
    }
}

// ---- launch ----
extern "C" void kernel_launch(void* const* d_in, const int* in_sizes, int n_in,
                              void* d_out, int out_size, void* d_ws, size_t ws_size,
                              hipStream_t stream) {
    const float* pred    = (const float*)d_in[0];
    const int*   target  = (const int*)d_in[1];
    const int*   parcel  = (const int*)d_in[2];
    const int*   cls_num = (const int*)d_in[3];
    char* ws = (char*)d_ws;

    if (ws_size >= kNeed40) {
        int*      off      = (int*)(ws + oOff);
        int*      cnt      = (int*)(ws + oCnt);
        int*      first    = (int*)(ws + oFirst);
        int*      binstart = (int*)(ws + oBin);
        float*    accum    = (float*)(ws + oAcc);
        int*      minb     = (int*)(ws + oMinb);      // aliases sortedV, dead after kB
        unsigned* sortedV  = (unsigned*)(ws + oSort);

        kA_hist<<<NB1, 1024, 0, stream>>>(target, parcel, off, minb);
        kB_colscan<<<kP / 256, 256, 0, stream>>>(off, minb, cnt, first, accum);
        k3_scan<<<1, 256, 0, stream>>>(cnt, binstart);
        if (ws_size >= kNeed64) {
            k5v<16><<<NB1, 1024, 0, stream>>>(target, parcel, pred, off, binstart, sortedV);
            k6v<16><<<kP / 4, 256, 0, stream>>>(sortedV, binstart, cnt, first, target, cls_num, accum);
        } else {
            k5v<10><<<NB1, 1024, 0, stream>>>(target, parcel, pred, off, binstart, sortedV);
            k6v<10><<<kP / 4, 256, 0, stream>>>(sortedV, binstart, cnt, first, target, cls_num, accum);
        }
        kE_out<<<1, 1, 0, stream>>>(accum, (float*)d_out);
    } else {
        float* seg   = (float*)(ws);
        float* cnt   = (float*)(ws + (size_t)kP * kC * 4);
        int*   first = (int*)(ws + (size_t)kP * kC * 4 + (size_t)kP * 4);
        float* accum = (float*)(ws + (size_t)kP * kC * 4 + (size_t)kP * 8);
        fb_init<<<(kP * kC + 255) / 256, 256, 0, stream>>>(seg, cnt, first, accum);
        fb_scatter<<<2048, 256, 0, stream>>>(pred, target, parcel, seg, cnt, first);
        fb_finalize<<<kP / 256, 256, 0, stream>>>(seg, cnt, first, target, cls_num, accum);
        kE_out<<<1, 1, 0, stream>>>(accum, (float*)d_out);
    }
}